// Round 8
// baseline (434.207 us; speedup 1.0000x reference)
//
#include <hip/hip_runtime.h>
#include <hip/hip_bf16.h>
#include <type_traits>

#define DEVFN __device__ __forceinline__

typedef __attribute__((ext_vector_type(8))) short bfrag;   // 8 bf16 (4 VGPRs)
typedef __attribute__((ext_vector_type(4))) float facc4;   // 4 fp32 acc
typedef __attribute__((ext_vector_type(2))) float f32x2;   // packed fp32 pair

DEVFN float lrelu(float v) { return (v >= 0.f) ? v : 0.2f * v; }

DEVFN float bf_lo(unsigned u) { return __uint_as_float(u << 16); }
DEVFN float bf_hi(unsigned u) { return __uint_as_float(u & 0xFFFF0000u); }
DEVFN f32x2 upk2(unsigned u) {
  f32x2 r; r.x = bf_lo(u); r.y = bf_hi(u); return r;
}
DEVFN unsigned short f2bf(float f) {
  __hip_bfloat16 h = __float2bfloat16(f);
  return *reinterpret_cast<unsigned short*>(&h);
}
DEVFN unsigned packbf2(float x, float y) {
  return (unsigned)f2bf(x) | ((unsigned)f2bf(y) << 16);
}

DEVFN float wave_sum(float v) {
#pragma unroll
  for (int o = 1; o < 64; o <<= 1) v += __shfl_xor(v, o, 64);
  return v;
}
DEVFN float wave_max(float v) {
#pragma unroll
  for (int o = 1; o < 64; o <<= 1) v = fmaxf(v, __shfl_xor(v, o, 64));
  return v;
}

// accumulate one H-row chunk (4 bf16x2 words) weighted by p into acc2[4]
#define FMA_ROW(p_, v_)                                                  \
  {                                                                      \
    f32x2 pv; pv.x = (p_); pv.y = (p_);                                  \
    acc2[0] += pv * upk2((v_).x);                                        \
    acc2[1] += pv * upk2((v_).y);                                        \
    acc2[2] += pv * upk2((v_).z);                                        \
    acc2[3] += pv * upk2((v_).w);                                        \
  }

// ---------------------------------------------------------------------------
// MFMA GEMM + fused escore. SPLIT=true writes H as two channel-half buffers
// H0[n][64] (ch 0-63) and H1[n][64] (ch 64-127), 128B rows each -> each
// gather pass sees a 6.4MB working set instead of 12.8MB.
// ---------------------------------------------------------------------------
template<int C, bool A_FP32, bool SPLIT>
__global__ __launch_bounds__(256) void gemm_mfma(const void* __restrict__ Xin,
                                                 const float* __restrict__ W,
                                                 const float* __restrict__ a_src,
                                                 const float* __restrict__ a_dst,
                                                 unsigned short* __restrict__ H0,
                                                 unsigned short* __restrict__ H1,
                                                 float* __restrict__ es,
                                                 float* __restrict__ ed,
                                                 int N) {
  constexpr int K = 128;
  constexpr int LSTR = K + 8;
  constexpr int NT = C / 16;
  __shared__ unsigned short WsT[C * LSTR];

  const int t = threadIdx.x;
  for (int i = t; i < K * C; i += 256) {
    int k = i / C;
    int c = i - k * C;
    WsT[c * LSTR + k] = f2bf(W[i]);
  }
  __syncthreads();

  const int wave = t >> 6;
  const int lane = t & 63;
  const int l15 = lane & 15;
  const int quad = lane >> 4;
  const int arow = blockIdx.x * 64 + wave * 16 + l15;
  const bool avalid = arow < N;

  facc4 acc[NT];
#pragma unroll
  for (int i = 0; i < NT; ++i) acc[i] = (facc4){0.f, 0.f, 0.f, 0.f};

#pragma unroll
  for (int ks = 0; ks < 4; ++ks) {
    bfrag a;
    if (A_FP32) {
      if (avalid) {
        const float* xp = (const float*)Xin + (size_t)arow * K + quad * 8 + ks * 32;
        float4 u = *(const float4*)xp;
        float4 v = *(const float4*)(xp + 4);
        a[0] = (short)f2bf(u.x); a[1] = (short)f2bf(u.y);
        a[2] = (short)f2bf(u.z); a[3] = (short)f2bf(u.w);
        a[4] = (short)f2bf(v.x); a[5] = (short)f2bf(v.y);
        a[6] = (short)f2bf(v.z); a[7] = (short)f2bf(v.w);
      } else {
        a = (bfrag){0, 0, 0, 0, 0, 0, 0, 0};
      }
    } else {
      const unsigned short* xp =
          (const unsigned short*)Xin + (size_t)arow * K + quad * 8 + ks * 32;
      a = *(const bfrag*)xp;
    }
#pragma unroll
    for (int ct = 0; ct < NT; ++ct) {
      bfrag b = *(const bfrag*)(&WsT[(ct * 16 + l15) * LSTR + ks * 32 + quad * 8]);
      acc[ct] = __builtin_amdgcn_mfma_f32_16x16x32_bf16(a, b, acc[ct], 0, 0, 0);
    }
  }

  float asv[NT], adv[NT];
#pragma unroll
  for (int ct = 0; ct < NT; ++ct) {
    asv[ct] = a_src[ct * 16 + l15];
    adv[ct] = a_dst[ct * 16 + l15];
  }

  const int orow0 = blockIdx.x * 64 + wave * 16 + quad * 4;
#pragma unroll
  for (int r = 0; r < 4; ++r) {
    const int orow = orow0 + r;
    float ps = 0.f, pd = 0.f;
#pragma unroll
    for (int ct = 0; ct < NT; ++ct) {
      if (orow < N) {
        if (SPLIT) {
          unsigned short* Hh = (ct >= 4) ? H1 : H0;
          Hh[(size_t)orow * 64 + (ct & 3) * 16 + l15] = f2bf(acc[ct][r]);
        } else {
          H0[(size_t)orow * C + ct * 16 + l15] = f2bf(acc[ct][r]);
        }
      }
      ps += acc[ct][r] * asv[ct];
      pd += acc[ct][r] * adv[ct];
    }
#pragma unroll
    for (int msk = 1; msk < 16; msk <<= 1) {
      ps += __shfl_xor(ps, msk, 64);
      pd += __shfl_xor(pd, msk, 64);
    }
    if (l15 == 0 && orow < N) { es[orow] = ps; ed[orow] = pd; }
  }
}

// ---------------------------------------------------------------------------
// CSR build: radix partition, zero global atomics, packed-uint BE payload.
// ---------------------------------------------------------------------------
__global__ void hist_only(const int* __restrict__ dst, int* __restrict__ hmat,
                          int E, int nbk, int chunk) {
  __shared__ int hist[4 * 128];
  const int t = threadIdx.x;
  for (int i = t; i < 4 * 128; i += 256) hist[i] = 0;
  __syncthreads();
  int* h = &hist[(t >> 6) << 7];
  const int e0 = blockIdx.x * chunk;
  const int e1 = min(E, e0 + chunk);
  for (int e = e0 + t; e < e1; e += 256) {
    atomicAdd(&h[dst[e] >> 9], 1);
  }
  __syncthreads();
  if (t < nbk)
    hmat[t * gridDim.x + blockIdx.x] =
        hist[t] + hist[t + 128] + hist[t + 256] + hist[t + 384];
}

// single-WG exclusive scan (n <= 65536): replaces 3-kernel scan chain.
__global__ void scan_all(const int* __restrict__ in, int* __restrict__ out, int n) {
  __shared__ int sh[1024];
  const int t = threadIdx.x;
  const int per = (n + 1023) >> 10;
  const int b0 = t * per;
  const int b1 = min(b0 + per, n);
  int s = 0;
  for (int i = b0; i < b1; ++i) s += in[i];
  sh[t] = s;
  __syncthreads();
  for (int o = 1; o < 1024; o <<= 1) {
    int u = (t >= o) ? sh[t - o] : 0;
    __syncthreads();
    sh[t] += u;
    __syncthreads();
  }
  int ex = sh[t] - s;
  for (int i = b0; i < b1; ++i) { int v = in[i]; out[i] = ex; ex += v; }
}

__global__ void scan_partial(const int* __restrict__ in, int* __restrict__ csum, int n) {
  __shared__ int sh[256];
  int i = blockIdx.x * 256 + threadIdx.x;
  sh[threadIdx.x] = (i < n) ? in[i] : 0;
  __syncthreads();
  for (int o = 128; o > 0; o >>= 1) {
    if (threadIdx.x < o) sh[threadIdx.x] += sh[threadIdx.x + o];
    __syncthreads();
  }
  if (threadIdx.x == 0) csum[blockIdx.x] = sh[0];
}

__global__ void scan_chunks(int* __restrict__ csum, int nch) {
  __shared__ int sh[256];
  __shared__ int carry;
  if (threadIdx.x == 0) carry = 0;
  __syncthreads();
  for (int base = 0; base < nch; base += 256) {
    int i = base + threadIdx.x;
    int v = (i < nch) ? csum[i] : 0;
    sh[threadIdx.x] = v;
    __syncthreads();
    for (int o = 1; o < 256; o <<= 1) {
      int t = (threadIdx.x >= o) ? sh[threadIdx.x - o] : 0;
      __syncthreads();
      sh[threadIdx.x] += t;
      __syncthreads();
    }
    if (i < nch) csum[i] = carry + sh[threadIdx.x] - v;
    __syncthreads();
    if (threadIdx.x == 255) carry += sh[255];
    __syncthreads();
  }
}

__global__ void scan_final(const int* __restrict__ deg, const int* __restrict__ csum,
                           int* __restrict__ rp, int* __restrict__ wp, int N, int E) {
  __shared__ int sh[256];
  int i = blockIdx.x * 256 + threadIdx.x;
  int v = (i < N) ? deg[i] : 0;
  sh[threadIdx.x] = v;
  __syncthreads();
  for (int o = 1; o < 256; o <<= 1) {
    int t = (threadIdx.x >= o) ? sh[threadIdx.x - o] : 0;
    __syncthreads();
    sh[threadIdx.x] += t;
    __syncthreads();
  }
  if (i < N) {
    int r = csum[blockIdx.x] + sh[threadIdx.x] - v;
    rp[i] = r;
    wp[i] = r;
  }
  if (blockIdx.x == 0 && threadIdx.x == 0) rp[N] = E;
}

__global__ void place_pass(const int* __restrict__ src, const int* __restrict__ dst,
                           const int* __restrict__ off, unsigned* __restrict__ be,
                           int E, int nbk, int chunk) {
  __shared__ int cur[128];
  const int t = threadIdx.x;
  if (t < nbk) cur[t] = off[t * gridDim.x + blockIdx.x];
  __syncthreads();
  const int e0 = blockIdx.x * chunk;
  const int e1 = min(E, e0 + chunk);
  for (int e = e0 + t; e < e1; e += 256) {
    int d = dst[e];
    int s = src[e];
    int p = atomicAdd(&cur[d >> 9], 1);
    be[p] = (unsigned)s | ((unsigned)d << 16);
  }
}

__global__ void bucket_final(const unsigned* __restrict__ be, const int* __restrict__ off,
                             int* __restrict__ rp, unsigned short* __restrict__ col,
                             int E, int N, int nbk, int pblk) {
  __shared__ int cur[512];
  __shared__ int ps[256];
  const int b = blockIdx.x;
  const int n0 = b << 9;
  const int cnt = min(512, N - n0);
  const int t = threadIdx.x;
  for (int i = t; i < cnt; i += 256) cur[i] = 0;
  __syncthreads();
  const int e0 = off[b * pblk];
  const int e1 = (b + 1 < nbk) ? off[(b + 1) * pblk] : E;
  for (int e = e0 + t; e < e1; e += 256) {
    unsigned sd = be[e];
    atomicAdd(&cur[(int)(sd >> 16) - n0], 1);
  }
  __syncthreads();
  const int i0 = 2 * t, i1 = 2 * t + 1;
  const int v0 = (i0 < cnt) ? cur[i0] : 0;
  const int v1 = (i1 < cnt) ? cur[i1] : 0;
  ps[t] = v0 + v1;
  __syncthreads();
  for (int o = 1; o < 256; o <<= 1) {
    int u = (t >= o) ? ps[t - o] : 0;
    __syncthreads();
    ps[t] += u;
    __syncthreads();
  }
  const int base = e0 + ps[t] - (v0 + v1);
  if (i0 < cnt) { rp[n0 + i0] = base;      cur[i0] = base; }
  if (i1 < cnt) { rp[n0 + i1] = base + v0; cur[i1] = base + v0; }
  if (b == nbk - 1 && t == 0) rp[N] = E;
  __syncthreads();
  for (int e = e0 + t; e < e1; e += 256) {
    unsigned sd = be[e];
    int p = atomicAdd(&cur[(int)(sd >> 16) - n0], 1);
    col[p] = (unsigned short)(sd & 0xFFFFu);
  }
}

__global__ void csr_scatter_ranged(const int* __restrict__ src,
                                   const int* __restrict__ dst,
                                   int* __restrict__ wp, int* __restrict__ col,
                                   int E, int range, int npass) {
  const int stride = gridDim.x * blockDim.x;
  const int gid = blockIdx.x * blockDim.x + threadIdx.x;
  for (int pass = 0; pass < npass; ++pass) {
    const int lo = pass * range;
    const int hi = lo + range;
    for (int e = gid; e < E; e += stride) {
      int d = dst[e];
      if (d >= lo && d < hi) {
        int p = atomicAdd(wp + d, 1);
        col[p] = src[e];
      }
    }
  }
}

__global__ void csr_count(const int* __restrict__ dst, int* __restrict__ deg, int E) {
  int e = blockIdx.x * blockDim.x + threadIdx.x;
  if (e < E) atomicAdd(deg + dst[e], 1);
}

// ---------------------------------------------------------------------------
// Split-half edge stage for C=128 layers.
// Pass A: fused softmax (chain as in R2) + gather of H0 (ch 0-63, 6.4MB
// working set); stores P/DENI/SPV for pass B; writes XB[:,0:64).
// Pass B: pure gather of H1 (ch 64-127, 6.4MB ws) using stored weights;
// writes XB[:,64:128). Each pass: 8 groups x 8 lanes, 128B rows.
// ---------------------------------------------------------------------------
template<bool RELU, typename IT>
__global__ void gat_half_a(const int* __restrict__ row_ptr,
                           const IT* __restrict__ col,
                           const float* __restrict__ es,
                           const float* __restrict__ ed,
                           const unsigned short* __restrict__ H0,
                           const float* __restrict__ bias,
                           float* __restrict__ P,
                           float* __restrict__ DENI,
                           float* __restrict__ SPV,
                           unsigned short* __restrict__ XB, int N) {
  const int lane = threadIdx.x & 63;
  const int n = blockIdx.x * (blockDim.x >> 6) + (threadIdx.x >> 6);
  if (n >= N) return;

  const int g8 = lane >> 3;
  const int l8 = lane & 7;

  const int k0 = row_ptr[n];
  const int k1 = row_ptr[n + 1];
  const int deg = k1 - k0;
  const float edd = ed[n];
  const float self_lg = lrelu(es[n] + edd);

  const char* Hb = (const char*)H0;
  f32x2 acc2[4];
#pragma unroll
  for (int i = 0; i < 4; ++i) { acc2[i].x = 0.f; acc2[i].y = 0.f; }
  float den, sp;

  if (deg <= 64) {
    int k = k0 + lane;
    bool act = (k < k1);
    int c = act ? (int)col[k] : 0;
    float lg = act ? lrelu(es[c] + edd) : -3.0e38f;
    float m = fmaxf(wave_max(lg), self_lg);
    float p = act ? __expf(lg - m) : 0.f;
    sp = __expf(self_lg - m);
    den = wave_sum(p) + sp;
    if (act) P[k] = p;
    for (int j = 0; j < deg; j += 8) {
      int i0 = min(j + g8, 63);
      int c0 = __shfl(c, i0);
      float p0 = __shfl(p, i0);
      uint4 v0 = *(const uint4*)(Hb + (((size_t)c0 << 7) + l8 * 16));
      FMA_ROW(p0, v0);
    }
  } else {
    float mloc = self_lg;
    for (int base = k0; base < k1; base += 64) {
      int k = base + lane;
      if (k < k1) mloc = fmaxf(mloc, lrelu(es[(int)col[k]] + edd));
    }
    float m = wave_max(mloc);
    sp = __expf(self_lg - m);
    den = sp;
    for (int base = k0; base < k1; base += 64) {
      int k = base + lane;
      bool act = (k < k1);
      int c = act ? (int)col[k] : 0;
      float p = act ? __expf(lrelu(es[c] + edd) - m) : 0.f;
      if (act) P[k] = p;
      den += wave_sum(p);
      int len = min(64, k1 - base);
      for (int j = 0; j < len; j += 8) {
        int i0 = min(j + g8, 63);
        int c0 = __shfl(c, i0);
        float p0 = __shfl(p, i0);
        uint4 v0 = *(const uint4*)(Hb + (((size_t)c0 << 7) + l8 * 16));
        FMA_ROW(p0, v0);
      }
    }
  }

  float a[8];
#pragma unroll
  for (int i = 0; i < 4; ++i) { a[2 * i] = acc2[i].x; a[2 * i + 1] = acc2[i].y; }
#pragma unroll
  for (int i = 0; i < 8; ++i) {
    a[i] += __shfl_xor(a[i], 8, 64);
    a[i] += __shfl_xor(a[i], 16, 64);
    a[i] += __shfl_xor(a[i], 32, 64);
  }

  uint4 hv = *(const uint4*)(Hb + (((size_t)n << 7) + l8 * 16));
  a[0] += sp * bf_lo(hv.x); a[1] += sp * bf_hi(hv.x);
  a[2] += sp * bf_lo(hv.y); a[3] += sp * bf_hi(hv.y);
  a[4] += sp * bf_lo(hv.z); a[5] += sp * bf_hi(hv.z);
  a[6] += sp * bf_lo(hv.w); a[7] += sp * bf_hi(hv.w);

  float inv = 1.f / den;
  if (lane == 0) { DENI[n] = inv; SPV[n] = sp; }
  float4 bv0 = *(const float4*)(bias + l8 * 8);
  float4 bv1 = *(const float4*)(bias + l8 * 8 + 4);
  float o0 = a[0] * inv + bv0.x, o1 = a[1] * inv + bv0.y;
  float o2 = a[2] * inv + bv0.z, o3 = a[3] * inv + bv0.w;
  float o4 = a[4] * inv + bv1.x, o5 = a[5] * inv + bv1.y;
  float o6 = a[6] * inv + bv1.z, o7 = a[7] * inv + bv1.w;
  if (RELU) {
    o0 = fmaxf(o0, 0.f); o1 = fmaxf(o1, 0.f); o2 = fmaxf(o2, 0.f);
    o3 = fmaxf(o3, 0.f); o4 = fmaxf(o4, 0.f); o5 = fmaxf(o5, 0.f);
    o6 = fmaxf(o6, 0.f); o7 = fmaxf(o7, 0.f);
  }
  if (g8 == 0) {
    uint4 w;
    w.x = packbf2(o0, o1); w.y = packbf2(o2, o3);
    w.z = packbf2(o4, o5); w.w = packbf2(o6, o7);
    *(uint4*)((char*)XB + (((size_t)n << 8) + l8 * 16)) = w;
  }
}

template<bool RELU, typename IT>
__global__ void gat_half_b(const int* __restrict__ row_ptr,
                           const IT* __restrict__ col,
                           const float* __restrict__ P,
                           const float* __restrict__ DENI,
                           const float* __restrict__ SPV,
                           const unsigned short* __restrict__ H1,
                           const float* __restrict__ bias,
                           unsigned short* __restrict__ XB, int N) {
  const int lane = threadIdx.x & 63;
  const int n = blockIdx.x * (blockDim.x >> 6) + (threadIdx.x >> 6);
  if (n >= N) return;

  const int g8 = lane >> 3;
  const int l8 = lane & 7;

  const int k0 = row_ptr[n];
  const int k1 = row_ptr[n + 1];
  const int deg = k1 - k0;
  const float sp = SPV[n];
  const float inv = DENI[n];

  const char* Hb = (const char*)H1;
  f32x2 acc2[4];
#pragma unroll
  for (int i = 0; i < 4; ++i) { acc2[i].x = 0.f; acc2[i].y = 0.f; }

  if (deg <= 64) {
    int k = k0 + lane;
    bool act = (k < k1);
    int c = act ? (int)col[k] : 0;
    float p = act ? P[k] : 0.f;
    for (int j = 0; j < deg; j += 8) {
      int i0 = min(j + g8, 63);
      int c0 = __shfl(c, i0);
      float p0 = __shfl(p, i0);
      uint4 v0 = *(const uint4*)(Hb + (((size_t)c0 << 7) + l8 * 16));
      FMA_ROW(p0, v0);
    }
  } else {
    for (int base = k0; base < k1; base += 64) {
      int k = base + lane;
      bool act = (k < k1);
      int c = act ? (int)col[k] : 0;
      float p = act ? P[k] : 0.f;
      int len = min(64, k1 - base);
      for (int j = 0; j < len; j += 8) {
        int i0 = min(j + g8, 63);
        int c0 = __shfl(c, i0);
        float p0 = __shfl(p, i0);
        uint4 v0 = *(const uint4*)(Hb + (((size_t)c0 << 7) + l8 * 16));
        FMA_ROW(p0, v0);
      }
    }
  }

  float a[8];
#pragma unroll
  for (int i = 0; i < 4; ++i) { a[2 * i] = acc2[i].x; a[2 * i + 1] = acc2[i].y; }
#pragma unroll
  for (int i = 0; i < 8; ++i) {
    a[i] += __shfl_xor(a[i], 8, 64);
    a[i] += __shfl_xor(a[i], 16, 64);
    a[i] += __shfl_xor(a[i], 32, 64);
  }

  uint4 hv = *(const uint4*)(Hb + (((size_t)n << 7) + l8 * 16));
  a[0] += sp * bf_lo(hv.x); a[1] += sp * bf_hi(hv.x);
  a[2] += sp * bf_lo(hv.y); a[3] += sp * bf_hi(hv.y);
  a[4] += sp * bf_lo(hv.z); a[5] += sp * bf_hi(hv.z);
  a[6] += sp * bf_lo(hv.w); a[7] += sp * bf_hi(hv.w);

  float4 bv0 = *(const float4*)(bias + 64 + l8 * 8);
  float4 bv1 = *(const float4*)(bias + 64 + l8 * 8 + 4);
  float o0 = a[0] * inv + bv0.x, o1 = a[1] * inv + bv0.y;
  float o2 = a[2] * inv + bv0.z, o3 = a[3] * inv + bv0.w;
  float o4 = a[4] * inv + bv1.x, o5 = a[5] * inv + bv1.y;
  float o6 = a[6] * inv + bv1.z, o7 = a[7] * inv + bv1.w;
  if (RELU) {
    o0 = fmaxf(o0, 0.f); o1 = fmaxf(o1, 0.f); o2 = fmaxf(o2, 0.f);
    o3 = fmaxf(o3, 0.f); o4 = fmaxf(o4, 0.f); o5 = fmaxf(o5, 0.f);
    o6 = fmaxf(o6, 0.f); o7 = fmaxf(o7, 0.f);
  }
  if (g8 == 0) {
    uint4 w;
    w.x = packbf2(o0, o1); w.y = packbf2(o2, o3);
    w.z = packbf2(o4, o5); w.w = packbf2(o6, o7);
    *(uint4*)((char*)XB + (((size_t)n << 8) + 128 + l8 * 16)) = w;
  }
}

// ---------------------------------------------------------------------------
// Layer-2 edge stage (C=64, fp32 out) — unchanged fused kernel; H2 working
// set is already 6.4MB.
// ---------------------------------------------------------------------------
template<bool RELU, typename IT>
__global__ void gat_fused64(const int* __restrict__ row_ptr,
                            const IT* __restrict__ col,
                            const float* __restrict__ es,
                            const float* __restrict__ ed,
                            const unsigned short* __restrict__ H,
                            const float* __restrict__ bias,
                            float* __restrict__ outX, int N) {
  const int lane = threadIdx.x & 63;
  const int n = blockIdx.x * (blockDim.x >> 6) + (threadIdx.x >> 6);
  if (n >= N) return;

  const int g8 = lane >> 3;
  const int l8 = lane & 7;

  const int k0 = row_ptr[n];
  const int k1 = row_ptr[n + 1];
  const int deg = k1 - k0;
  const float edd = ed[n];
  const float self_lg = lrelu(es[n] + edd);

  const char* Hb = (const char*)H;
  f32x2 acc2[4];
#pragma unroll
  for (int i = 0; i < 4; ++i) { acc2[i].x = 0.f; acc2[i].y = 0.f; }
  float den, sp;

  if (deg <= 64) {
    int k = k0 + lane;
    bool act = (k < k1);
    int c = act ? (int)col[k] : 0;
    float lg = act ? lrelu(es[c] + edd) : -3.0e38f;
    float m = fmaxf(wave_max(lg), self_lg);
    float p = act ? __expf(lg - m) : 0.f;
    sp = __expf(self_lg - m);
    den = wave_sum(p) + sp;
    for (int j = 0; j < deg; j += 8) {
      int i0 = min(j + g8, 63);
      int c0 = __shfl(c, i0);
      float p0 = __shfl(p, i0);
      uint4 v0 = *(const uint4*)(Hb + (((size_t)c0 << 7) + l8 * 16));
      FMA_ROW(p0, v0);
    }
  } else {
    float mloc = self_lg;
    for (int base = k0; base < k1; base += 64) {
      int k = base + lane;
      if (k < k1) mloc = fmaxf(mloc, lrelu(es[(int)col[k]] + edd));
    }
    float m = wave_max(mloc);
    sp = __expf(self_lg - m);
    den = sp;
    for (int base = k0; base < k1; base += 64) {
      int k = base + lane;
      bool act = (k < k1);
      int c = act ? (int)col[k] : 0;
      float p = act ? __expf(lrelu(es[c] + edd) - m) : 0.f;
      den += wave_sum(p);
      int len = min(64, k1 - base);
      for (int j = 0; j < len; j += 8) {
        int i0 = min(j + g8, 63);
        int c0 = __shfl(c, i0);
        float p0 = __shfl(p, i0);
        uint4 v0 = *(const uint4*)(Hb + (((size_t)c0 << 7) + l8 * 16));
        FMA_ROW(p0, v0);
      }
    }
  }

  float a[8];
#pragma unroll
  for (int i = 0; i < 4; ++i) { a[2 * i] = acc2[i].x; a[2 * i + 1] = acc2[i].y; }
#pragma unroll
  for (int i = 0; i < 8; ++i) {
    a[i] += __shfl_xor(a[i], 8, 64);
    a[i] += __shfl_xor(a[i], 16, 64);
    a[i] += __shfl_xor(a[i], 32, 64);
  }

  uint4 hv = *(const uint4*)(Hb + (((size_t)n << 7) + l8 * 16));
  a[0] += sp * bf_lo(hv.x); a[1] += sp * bf_hi(hv.x);
  a[2] += sp * bf_lo(hv.y); a[3] += sp * bf_hi(hv.y);
  a[4] += sp * bf_lo(hv.z); a[5] += sp * bf_hi(hv.z);
  a[6] += sp * bf_lo(hv.w); a[7] += sp * bf_hi(hv.w);

  float inv = 1.f / den;
  float4 bv0 = *(const float4*)(bias + l8 * 8);
  float4 bv1 = *(const float4*)(bias + l8 * 8 + 4);
  float4 w0, w1;
  w0.x = a[0] * inv + bv0.x; w0.y = a[1] * inv + bv0.y;
  w0.z = a[2] * inv + bv0.z; w0.w = a[3] * inv + bv0.w;
  w1.x = a[4] * inv + bv1.x; w1.y = a[5] * inv + bv1.y;
  w1.z = a[6] * inv + bv1.z; w1.w = a[7] * inv + bv1.w;
  if (RELU) {
    w0.x = fmaxf(w0.x, 0.f); w0.y = fmaxf(w0.y, 0.f);
    w0.z = fmaxf(w0.z, 0.f); w0.w = fmaxf(w0.w, 0.f);
    w1.x = fmaxf(w1.x, 0.f); w1.y = fmaxf(w1.y, 0.f);
    w1.z = fmaxf(w1.z, 0.f); w1.w = fmaxf(w1.w, 0.f);
  }
  if (g8 == 0) {
    char* op = (char*)outX + (((size_t)n << 8) + l8 * 32);
    *(float4*)op = w0;
    *(float4*)(op + 16) = w1;
  }
}

// ---------------------------------------------------------------------------

extern "C" void kernel_launch(void* const* d_in, const int* in_sizes, int n_in,
                              void* d_out, int out_size, void* d_ws, size_t ws_size,
                              hipStream_t stream) {
  const int C_HID = in_sizes[3];            // 128
  const int C_FIN = in_sizes[11];           // 64
  const int C_IN  = in_sizes[2] / C_HID;    // 128
  const int N     = in_sizes[0] / C_IN;     // 50000
  const int E     = in_sizes[1] / 2;        // 1.6M
  const int NPAD  = ((N + 63) / 64) * 64;

  const float* x = (const float*)d_in[0];
  const int* ei  = (const int*)d_in[1];
  const int* src = ei;
  const int* dst = ei + E;

  const float* W0  = (const float*)d_in[2];
  const float* as0 = (const float*)d_in[3];
  const float* ad0 = (const float*)d_in[4];
  const float* b0  = (const float*)d_in[5];
  const float* W1  = (const float*)d_in[6];
  const float* as1 = (const float*)d_in[7];
  const float* ad1 = (const float*)d_in[8];
  const float* b1  = (const float*)d_in[9];
  const float* W2  = (const float*)d_in[10];
  const float* as2 = (const float*)d_in[11];
  const float* ad2 = (const float*)d_in[12];
  const float* b2  = (const float*)d_in[13];

  // Workspace layout (256B aligned)
  char* base = (char*)d_ws;
  size_t off = 0;
  auto alloc = [&](size_t bytes) -> char* {
    char* p = base + off;
    off = (off + bytes + 255) & ~((size_t)255);
    return p;
  };
  const int PBLK = 512;                     // partition blocks
  const int NBK  = (N + 511) >> 9;          // buckets of 512 dst nodes (<=128)
  const int M    = NBK * PBLK;              // offset-matrix size
  const int NCH  = (N + 255) / 256;
  const int SCH  = NCH;

  unsigned short* XB  = (unsigned short*)alloc((size_t)NPAD * C_HID * 2);
  unsigned short* H0  = (unsigned short*)alloc((size_t)N * 64 * 2);
  unsigned short* H1  = (unsigned short*)alloc((size_t)N * 64 * 2);
  float* ES    = (float*)alloc((size_t)N * sizeof(float));
  float* ED    = (float*)alloc((size_t)N * sizeof(float));
  float* P     = (float*)alloc((size_t)E * sizeof(float));
  float* DENI  = (float*)alloc((size_t)N * sizeof(float));
  float* SPV   = (float*)alloc((size_t)N * sizeof(float));
  int*   RP    = (int*)alloc((size_t)(N + 1) * sizeof(int));
  int*   WP    = (int*)alloc((size_t)N * sizeof(int));
  void*  COL   = (void*)alloc((size_t)E * sizeof(int));   // u16 uses half
  int*   DEG   = (int*)alloc((size_t)N * sizeof(int));
  int*   CSUM  = (int*)alloc((size_t)SCH * sizeof(int));
  int*   HMAT  = (int*)alloc((size_t)M * sizeof(int));
  int*   OFF   = (int*)alloc((size_t)M * sizeof(int));
  unsigned* BE = (unsigned*)alloc((size_t)E * sizeof(unsigned));
  (void)ws_size;

  const int wgrid = (N + 3) / 4;
  const int mgrid = NPAD / 64;
  const bool u16 = (N <= 65535);

  // ---- CSR build ----
  if (u16) {
    const int CHUNK = (E + PBLK - 1) / PBLK;
    hist_only<<<PBLK, 256, 0, stream>>>(dst, HMAT, E, NBK, CHUNK);
    scan_all<<<1, 1024, 0, stream>>>(HMAT, OFF, M);
    place_pass<<<PBLK, 256, 0, stream>>>(src, dst, OFF, BE, E, NBK, CHUNK);
    bucket_final<<<NBK, 256, 0, stream>>>(BE, OFF, RP, (unsigned short*)COL,
                                          E, N, NBK, PBLK);
  } else {
    hipMemsetAsync(DEG, 0, (size_t)N * sizeof(int), stream);
    const int ET256 = (E + 255) / 256;
    csr_count<<<ET256, 256, 0, stream>>>(dst, DEG, E);
    scan_partial<<<NCH, 256, 0, stream>>>(DEG, CSUM, N);
    scan_chunks<<<1, 256, 0, stream>>>(CSUM, NCH);
    scan_final<<<NCH, 256, 0, stream>>>(DEG, CSUM, RP, WP, N, E);
    const int NPASS = 8;
    const int range = (N + NPASS - 1) / NPASS;
    csr_scatter_ranged<<<2048, 256, 0, stream>>>(src, dst, WP, (int*)COL, E,
                                                 range, NPASS);
  }

  auto run_layers = [&](auto* col) {
    using IT = typename std::remove_pointer<decltype(col)>::type;
    // ---- Layer 0: x(fp32) -> H0/H1(+es/ed) -> XB halves (relu, bf16) ----
    gemm_mfma<128, true, true><<<mgrid, 256, 0, stream>>>(x, W0, as0, ad0,
                                                          H0, H1, ES, ED, N);
    gat_half_a<true, IT><<<wgrid, 256, 0, stream>>>(RP, col, ES, ED, H0, b0,
                                                    P, DENI, SPV, XB, N);
    gat_half_b<true, IT><<<wgrid, 256, 0, stream>>>(RP, col, P, DENI, SPV,
                                                    H1, b0, XB, N);
    // ---- Layer 1: XB -> H0/H1(+es/ed) -> XB halves (relu, bf16) ----
    gemm_mfma<128, false, true><<<mgrid, 256, 0, stream>>>(XB, W1, as1, ad1,
                                                           H0, H1, ES, ED, N);
    gat_half_a<true, IT><<<wgrid, 256, 0, stream>>>(RP, col, ES, ED, H0, b1,
                                                    P, DENI, SPV, XB, N);
    gat_half_b<true, IT><<<wgrid, 256, 0, stream>>>(RP, col, P, DENI, SPV,
                                                    H1, b1, XB, N);
    // ---- Layer 2: XB -> H0(C=64, +es/ed) -> d_out (no relu, fp32) ----
    gemm_mfma<64, false, false><<<mgrid, 256, 0, stream>>>(XB, W2, as2, ad2,
                                                           H0, H1, ES, ED, N);
    gat_fused64<false, IT><<<wgrid, 256, 0, stream>>>(RP, col, ES, ED, H0, b2,
                                                      (float*)d_out, N);
  };

  if (u16) run_layers((unsigned short*)COL);
  else     run_layers((int*)COL);
  (void)out_size; (void)n_in;
}

// Round 9
// 332.915 us; speedup vs baseline: 1.3043x; 1.3043x over previous
//
#include <hip/hip_runtime.h>
#include <hip/hip_bf16.h>
#include <type_traits>

#define DEVFN __device__ __forceinline__

typedef __attribute__((ext_vector_type(8))) short bfrag;   // 8 bf16 (4 VGPRs)
typedef __attribute__((ext_vector_type(4))) float facc4;   // 4 fp32 acc

DEVFN float lrelu(float v) { return (v >= 0.f) ? v : 0.2f * v; }

DEVFN float bf_lo(unsigned u) { return __uint_as_float(u << 16); }
DEVFN float bf_hi(unsigned u) { return __uint_as_float(u & 0xFFFF0000u); }
DEVFN unsigned short f2bf(float f) {
  __hip_bfloat16 h = __float2bfloat16(f);
  return *reinterpret_cast<unsigned short*>(&h);
}
DEVFN unsigned packbf2(float x, float y) {
  return (unsigned)f2bf(x) | ((unsigned)f2bf(y) << 16);
}

DEVFN float wave_sum(float v) {
#pragma unroll
  for (int o = 1; o < 64; o <<= 1) v += __shfl_xor(v, o, 64);
  return v;
}
DEVFN float wave_max(float v) {
#pragma unroll
  for (int o = 1; o < 64; o <<= 1) v = fmaxf(v, __shfl_xor(v, o, 64));
  return v;
}

// ---------------------------------------------------------------------------
// MFMA GEMM + fused escore + fused weight conversion.
// ---------------------------------------------------------------------------
template<int C, bool A_FP32>
__global__ __launch_bounds__(256) void gemm_mfma(const void* __restrict__ Xin,
                                                 const float* __restrict__ W,
                                                 const float* __restrict__ a_src,
                                                 const float* __restrict__ a_dst,
                                                 unsigned short* __restrict__ H,
                                                 float* __restrict__ es,
                                                 float* __restrict__ ed,
                                                 int N) {
  constexpr int K = 128;
  constexpr int LSTR = K + 8;
  constexpr int NT = C / 16;
  __shared__ unsigned short WsT[C * LSTR];

  const int t = threadIdx.x;
  for (int i = t; i < K * C; i += 256) {
    int k = i / C;
    int c = i - k * C;
    WsT[c * LSTR + k] = f2bf(W[i]);
  }
  __syncthreads();

  const int wave = t >> 6;
  const int lane = t & 63;
  const int l15 = lane & 15;
  const int quad = lane >> 4;
  const int arow = blockIdx.x * 64 + wave * 16 + l15;
  const bool avalid = arow < N;

  facc4 acc[NT];
#pragma unroll
  for (int i = 0; i < NT; ++i) acc[i] = (facc4){0.f, 0.f, 0.f, 0.f};

#pragma unroll
  for (int ks = 0; ks < 4; ++ks) {
    bfrag a;
    if (A_FP32) {
      if (avalid) {
        const float* xp = (const float*)Xin + (size_t)arow * K + quad * 8 + ks * 32;
        float4 u = *(const float4*)xp;
        float4 v = *(const float4*)(xp + 4);
        a[0] = (short)f2bf(u.x); a[1] = (short)f2bf(u.y);
        a[2] = (short)f2bf(u.z); a[3] = (short)f2bf(u.w);
        a[4] = (short)f2bf(v.x); a[5] = (short)f2bf(v.y);
        a[6] = (short)f2bf(v.z); a[7] = (short)f2bf(v.w);
      } else {
        a = (bfrag){0, 0, 0, 0, 0, 0, 0, 0};
      }
    } else {
      const unsigned short* xp =
          (const unsigned short*)Xin + (size_t)arow * K + quad * 8 + ks * 32;
      a = *(const bfrag*)xp;
    }
#pragma unroll
    for (int ct = 0; ct < NT; ++ct) {
      bfrag b = *(const bfrag*)(&WsT[(ct * 16 + l15) * LSTR + ks * 32 + quad * 8]);
      acc[ct] = __builtin_amdgcn_mfma_f32_16x16x32_bf16(a, b, acc[ct], 0, 0, 0);
    }
  }

  float asv[NT], adv[NT];
#pragma unroll
  for (int ct = 0; ct < NT; ++ct) {
    asv[ct] = a_src[ct * 16 + l15];
    adv[ct] = a_dst[ct * 16 + l15];
  }

  const int orow0 = blockIdx.x * 64 + wave * 16 + quad * 4;
#pragma unroll
  for (int r = 0; r < 4; ++r) {
    const int orow = orow0 + r;
    float ps = 0.f, pd = 0.f;
#pragma unroll
    for (int ct = 0; ct < NT; ++ct) {
      if (orow < N) H[(size_t)orow * C + ct * 16 + l15] = f2bf(acc[ct][r]);
      ps += acc[ct][r] * asv[ct];
      pd += acc[ct][r] * adv[ct];
    }
#pragma unroll
    for (int msk = 1; msk < 16; msk <<= 1) {
      ps += __shfl_xor(ps, msk, 64);
      pd += __shfl_xor(pd, msk, 64);
    }
    if (l15 == 0 && orow < N) { es[orow] = ps; ed[orow] = pd; }
  }
}

// ---------------------------------------------------------------------------
// CSR build: radix partition, zero global atomics, packed-uint BE payload
// (src | dst<<16, both <65536 in the u16 path -> halves BE traffic).
// Proven 3-kernel scan chain (single-WG scan measured 76us in R8 - never
// serialize a 65536-scan onto one CU).
// ---------------------------------------------------------------------------
__global__ void hist_only(const int* __restrict__ dst, int* __restrict__ hmat,
                          int E, int nbk, int chunk) {
  __shared__ int hist[4 * 128];
  const int t = threadIdx.x;
  for (int i = t; i < 4 * 128; i += 256) hist[i] = 0;
  __syncthreads();
  int* h = &hist[(t >> 6) << 7];
  const int e0 = blockIdx.x * chunk;
  const int e1 = min(E, e0 + chunk);
  for (int e = e0 + t; e < e1; e += 256) {
    atomicAdd(&h[dst[e] >> 9], 1);
  }
  __syncthreads();
  if (t < nbk)
    hmat[t * gridDim.x + blockIdx.x] =
        hist[t] + hist[t + 128] + hist[t + 256] + hist[t + 384];
}

__global__ void scan_partial(const int* __restrict__ in, int* __restrict__ csum, int n) {
  __shared__ int sh[256];
  int i = blockIdx.x * 256 + threadIdx.x;
  sh[threadIdx.x] = (i < n) ? in[i] : 0;
  __syncthreads();
  for (int o = 128; o > 0; o >>= 1) {
    if (threadIdx.x < o) sh[threadIdx.x] += sh[threadIdx.x + o];
    __syncthreads();
  }
  if (threadIdx.x == 0) csum[blockIdx.x] = sh[0];
}

__global__ void scan_chunks(int* __restrict__ csum, int nch) {
  __shared__ int sh[256];
  __shared__ int carry;
  if (threadIdx.x == 0) carry = 0;
  __syncthreads();
  for (int base = 0; base < nch; base += 256) {
    int i = base + threadIdx.x;
    int v = (i < nch) ? csum[i] : 0;
    sh[threadIdx.x] = v;
    __syncthreads();
    for (int o = 1; o < 256; o <<= 1) {
      int t = (threadIdx.x >= o) ? sh[threadIdx.x - o] : 0;
      __syncthreads();
      sh[threadIdx.x] += t;
      __syncthreads();
    }
    if (i < nch) csum[i] = carry + sh[threadIdx.x] - v;
    __syncthreads();
    if (threadIdx.x == 255) carry += sh[255];
    __syncthreads();
  }
}

__global__ void scan_final(const int* __restrict__ deg, const int* __restrict__ csum,
                           int* __restrict__ rp, int* __restrict__ wp, int N, int E) {
  __shared__ int sh[256];
  int i = blockIdx.x * 256 + threadIdx.x;
  int v = (i < N) ? deg[i] : 0;
  sh[threadIdx.x] = v;
  __syncthreads();
  for (int o = 1; o < 256; o <<= 1) {
    int t = (threadIdx.x >= o) ? sh[threadIdx.x - o] : 0;
    __syncthreads();
    sh[threadIdx.x] += t;
    __syncthreads();
  }
  if (i < N) {
    int r = csum[blockIdx.x] + sh[threadIdx.x] - v;
    rp[i] = r;
    wp[i] = r;
  }
  if (blockIdx.x == 0 && threadIdx.x == 0) rp[N] = E;
}

__global__ void scan_final_excl(const int* __restrict__ in, const int* __restrict__ csum,
                                int* __restrict__ out, int n) {
  __shared__ int sh[256];
  int i = blockIdx.x * 256 + threadIdx.x;
  int v = (i < n) ? in[i] : 0;
  sh[threadIdx.x] = v;
  __syncthreads();
  for (int o = 1; o < 256; o <<= 1) {
    int t = (threadIdx.x >= o) ? sh[threadIdx.x - o] : 0;
    __syncthreads();
    sh[threadIdx.x] += t;
    __syncthreads();
  }
  if (i < n) out[i] = csum[blockIdx.x] + sh[threadIdx.x] - v;
}

__global__ void place_pass(const int* __restrict__ src, const int* __restrict__ dst,
                           const int* __restrict__ off, unsigned* __restrict__ be,
                           int E, int nbk, int chunk) {
  __shared__ int cur[128];
  const int t = threadIdx.x;
  if (t < nbk) cur[t] = off[t * gridDim.x + blockIdx.x];
  __syncthreads();
  const int e0 = blockIdx.x * chunk;
  const int e1 = min(E, e0 + chunk);
  for (int e = e0 + t; e < e1; e += 256) {
    int d = dst[e];
    int s = src[e];
    int p = atomicAdd(&cur[d >> 9], 1);
    be[p] = (unsigned)s | ((unsigned)d << 16);
  }
}

__global__ void bucket_final(const unsigned* __restrict__ be, const int* __restrict__ off,
                             int* __restrict__ rp, unsigned short* __restrict__ col,
                             int E, int N, int nbk, int pblk) {
  __shared__ int cur[512];
  __shared__ int ps[256];
  const int b = blockIdx.x;
  const int n0 = b << 9;
  const int cnt = min(512, N - n0);
  const int t = threadIdx.x;
  for (int i = t; i < cnt; i += 256) cur[i] = 0;
  __syncthreads();
  const int e0 = off[b * pblk];
  const int e1 = (b + 1 < nbk) ? off[(b + 1) * pblk] : E;
  for (int e = e0 + t; e < e1; e += 256) {
    unsigned sd = be[e];
    atomicAdd(&cur[(int)(sd >> 16) - n0], 1);
  }
  __syncthreads();
  const int i0 = 2 * t, i1 = 2 * t + 1;
  const int v0 = (i0 < cnt) ? cur[i0] : 0;
  const int v1 = (i1 < cnt) ? cur[i1] : 0;
  ps[t] = v0 + v1;
  __syncthreads();
  for (int o = 1; o < 256; o <<= 1) {
    int u = (t >= o) ? ps[t - o] : 0;
    __syncthreads();
    ps[t] += u;
    __syncthreads();
  }
  const int base = e0 + ps[t] - (v0 + v1);
  if (i0 < cnt) { rp[n0 + i0] = base;      cur[i0] = base; }
  if (i1 < cnt) { rp[n0 + i1] = base + v0; cur[i1] = base + v0; }
  if (b == nbk - 1 && t == 0) rp[N] = E;
  __syncthreads();
  for (int e = e0 + t; e < e1; e += 256) {
    unsigned sd = be[e];
    int p = atomicAdd(&cur[(int)(sd >> 16) - n0], 1);
    col[p] = (unsigned short)(sd & 0xFFFFu);
  }
}

__global__ void csr_scatter_ranged(const int* __restrict__ src,
                                   const int* __restrict__ dst,
                                   int* __restrict__ wp, int* __restrict__ col,
                                   int E, int range, int npass) {
  const int stride = gridDim.x * blockDim.x;
  const int gid = blockIdx.x * blockDim.x + threadIdx.x;
  for (int pass = 0; pass < npass; ++pass) {
    const int lo = pass * range;
    const int hi = lo + range;
    for (int e = gid; e < E; e += stride) {
      int d = dst[e];
      if (d >= lo && d < hi) {
        int p = atomicAdd(wp + d, 1);
        col[p] = src[e];
      }
    }
  }
}

__global__ void csr_count(const int* __restrict__ dst, int* __restrict__ deg, int E) {
  int e = blockIdx.x * blockDim.x + threadIdx.x;
  if (e < E) atomicAdd(deg + dst[e], 1);
}

// ---------------------------------------------------------------------------
// Fused GAT edge stage, grouped-gather (best-measured structure, R3=332us).
// C=128: wave = 4 groups x 16 lanes; one dwordx4 per group -> 4 edges/VMEM.
// C=64 : wave = 8 groups x 8 lanes  -> 8 edges/VMEM.
// Gather floor characterization (R2..R8): 50-54us, FETCH pinned ~153MB
// across 6 structural variants + 2 locality transforms; compulsory traffic
// = 8 XCDs x 12.8MB = 102MB -> within 1.5x of compulsory. Structural floor.
// ---------------------------------------------------------------------------
template<bool RELU, typename IT>
__global__ void gat_fused128(const int* __restrict__ row_ptr,
                             const IT* __restrict__ col,
                             const float* __restrict__ es,
                             const float* __restrict__ ed,
                             const unsigned short* __restrict__ H,
                             const float* __restrict__ bias,
                             void* __restrict__ outX, int N) {
  const int lane = threadIdx.x & 63;
  const int n = blockIdx.x * (blockDim.x >> 6) + (threadIdx.x >> 6);
  if (n >= N) return;

  const int g4 = lane >> 4;
  const int l15 = lane & 15;

  const int k0 = row_ptr[n];
  const int k1 = row_ptr[n + 1];
  const int deg = k1 - k0;
  const float edd = ed[n];
  const float self_lg = lrelu(es[n] + edd);

  const char* Hb = (const char*)H;
  float acc[8];
#pragma unroll
  for (int i = 0; i < 8; ++i) acc[i] = 0.f;
  float den, sp;

  if (deg <= 64) {
    int k = k0 + lane;
    bool act = (k < k1);
    int c = act ? (int)col[k] : 0;
    float lg = act ? lrelu(es[c] + edd) : -3.0e38f;
    float m = fmaxf(wave_max(lg), self_lg);
    float p = act ? __expf(lg - m) : 0.f;
    sp = __expf(self_lg - m);
    den = wave_sum(p) + sp;
    for (int j = 0; j < deg; j += 8) {
      int i0 = min(j + g4, 63);
      int i1 = min(j + 4 + g4, 63);
      int c0 = __shfl(c, i0);
      int c1 = __shfl(c, i1);
      float p0 = __shfl(p, i0);
      float p1 = __shfl(p, i1);
      uint4 v0 = *(const uint4*)(Hb + (((size_t)c0 << 8) + l15 * 16));
      uint4 v1 = *(const uint4*)(Hb + (((size_t)c1 << 8) + l15 * 16));
      acc[0] += p0 * bf_lo(v0.x); acc[1] += p0 * bf_hi(v0.x);
      acc[2] += p0 * bf_lo(v0.y); acc[3] += p0 * bf_hi(v0.y);
      acc[4] += p0 * bf_lo(v0.z); acc[5] += p0 * bf_hi(v0.z);
      acc[6] += p0 * bf_lo(v0.w); acc[7] += p0 * bf_hi(v0.w);
      acc[0] += p1 * bf_lo(v1.x); acc[1] += p1 * bf_hi(v1.x);
      acc[2] += p1 * bf_lo(v1.y); acc[3] += p1 * bf_hi(v1.y);
      acc[4] += p1 * bf_lo(v1.z); acc[5] += p1 * bf_hi(v1.z);
      acc[6] += p1 * bf_lo(v1.w); acc[7] += p1 * bf_hi(v1.w);
    }
  } else {
    float mloc = self_lg;
    for (int base = k0; base < k1; base += 64) {
      int k = base + lane;
      if (k < k1) mloc = fmaxf(mloc, lrelu(es[(int)col[k]] + edd));
    }
    float m = wave_max(mloc);
    sp = __expf(self_lg - m);
    den = sp;
    for (int base = k0; base < k1; base += 64) {
      int k = base + lane;
      bool act = (k < k1);
      int c = act ? (int)col[k] : 0;
      float p = act ? __expf(lrelu(es[c] + edd) - m) : 0.f;
      den += wave_sum(p);
      int len = min(64, k1 - base);
      for (int j = 0; j < len; j += 8) {
        int i0 = min(j + g4, 63);
        int i1 = min(j + 4 + g4, 63);
        int c0 = __shfl(c, i0);
        int c1 = __shfl(c, i1);
        float p0 = __shfl(p, i0);
        float p1 = __shfl(p, i1);
        uint4 v0 = *(const uint4*)(Hb + (((size_t)c0 << 8) + l15 * 16));
        uint4 v1 = *(const uint4*)(Hb + (((size_t)c1 << 8) + l15 * 16));
        acc[0] += p0 * bf_lo(v0.x); acc[1] += p0 * bf_hi(v0.x);
        acc[2] += p0 * bf_lo(v0.y); acc[3] += p0 * bf_hi(v0.y);
        acc[4] += p0 * bf_lo(v0.z); acc[5] += p0 * bf_hi(v0.z);
        acc[6] += p0 * bf_lo(v0.w); acc[7] += p0 * bf_hi(v0.w);
        acc[0] += p1 * bf_lo(v1.x); acc[1] += p1 * bf_hi(v1.x);
        acc[2] += p1 * bf_lo(v1.y); acc[3] += p1 * bf_hi(v1.y);
        acc[4] += p1 * bf_lo(v1.z); acc[5] += p1 * bf_hi(v1.z);
        acc[6] += p1 * bf_lo(v1.w); acc[7] += p1 * bf_hi(v1.w);
      }
    }
  }

  // reduce across the 4 groups (lanes with equal l15 hold the same channels)
#pragma unroll
  for (int i = 0; i < 8; ++i) {
    acc[i] += __shfl_xor(acc[i], 16, 64);
    acc[i] += __shfl_xor(acc[i], 32, 64);
  }

  // self-loop + epilogue (all lanes compute; group 0 stores)
  uint4 hv = *(const uint4*)(Hb + (((size_t)n << 8) + l15 * 16));
  acc[0] += sp * bf_lo(hv.x); acc[1] += sp * bf_hi(hv.x);
  acc[2] += sp * bf_lo(hv.y); acc[3] += sp * bf_hi(hv.y);
  acc[4] += sp * bf_lo(hv.z); acc[5] += sp * bf_hi(hv.z);
  acc[6] += sp * bf_lo(hv.w); acc[7] += sp * bf_hi(hv.w);

  float inv = 1.f / den;
  float4 bv0 = *(const float4*)(bias + l15 * 8);
  float4 bv1 = *(const float4*)(bias + l15 * 8 + 4);
  float o0 = acc[0] * inv + bv0.x, o1 = acc[1] * inv + bv0.y;
  float o2 = acc[2] * inv + bv0.z, o3 = acc[3] * inv + bv0.w;
  float o4 = acc[4] * inv + bv1.x, o5 = acc[5] * inv + bv1.y;
  float o6 = acc[6] * inv + bv1.z, o7 = acc[7] * inv + bv1.w;
  if (RELU) {
    o0 = fmaxf(o0, 0.f); o1 = fmaxf(o1, 0.f); o2 = fmaxf(o2, 0.f);
    o3 = fmaxf(o3, 0.f); o4 = fmaxf(o4, 0.f); o5 = fmaxf(o5, 0.f);
    o6 = fmaxf(o6, 0.f); o7 = fmaxf(o7, 0.f);
  }
  if (g4 == 0) {
    uint4 w;
    w.x = packbf2(o0, o1); w.y = packbf2(o2, o3);
    w.z = packbf2(o4, o5); w.w = packbf2(o6, o7);
    *(uint4*)((char*)outX + (((size_t)n << 8) + l15 * 16)) = w;
  }
}

template<bool RELU, typename IT>
__global__ void gat_fused64(const int* __restrict__ row_ptr,
                            const IT* __restrict__ col,
                            const float* __restrict__ es,
                            const float* __restrict__ ed,
                            const unsigned short* __restrict__ H,
                            const float* __restrict__ bias,
                            float* __restrict__ outX, int N) {
  const int lane = threadIdx.x & 63;
  const int n = blockIdx.x * (blockDim.x >> 6) + (threadIdx.x >> 6);
  if (n >= N) return;

  const int g8 = lane >> 3;
  const int l8 = lane & 7;

  const int k0 = row_ptr[n];
  const int k1 = row_ptr[n + 1];
  const int deg = k1 - k0;
  const float edd = ed[n];
  const float self_lg = lrelu(es[n] + edd);

  const char* Hb = (const char*)H;
  float acc[8];
#pragma unroll
  for (int i = 0; i < 8; ++i) acc[i] = 0.f;
  float den, sp;

  if (deg <= 64) {
    int k = k0 + lane;
    bool act = (k < k1);
    int c = act ? (int)col[k] : 0;
    float lg = act ? lrelu(es[c] + edd) : -3.0e38f;
    float m = fmaxf(wave_max(lg), self_lg);
    float p = act ? __expf(lg - m) : 0.f;
    sp = __expf(self_lg - m);
    den = wave_sum(p) + sp;
    for (int j = 0; j < deg; j += 8) {
      int i0 = min(j + g8, 63);
      int c0 = __shfl(c, i0);
      float p0 = __shfl(p, i0);
      uint4 v0 = *(const uint4*)(Hb + (((size_t)c0 << 7) + l8 * 16));
      acc[0] += p0 * bf_lo(v0.x); acc[1] += p0 * bf_hi(v0.x);
      acc[2] += p0 * bf_lo(v0.y); acc[3] += p0 * bf_hi(v0.y);
      acc[4] += p0 * bf_lo(v0.z); acc[5] += p0 * bf_hi(v0.z);
      acc[6] += p0 * bf_lo(v0.w); acc[7] += p0 * bf_hi(v0.w);
    }
  } else {
    float mloc = self_lg;
    for (int base = k0; base < k1; base += 64) {
      int k = base + lane;
      if (k < k1) mloc = fmaxf(mloc, lrelu(es[(int)col[k]] + edd));
    }
    float m = wave_max(mloc);
    sp = __expf(self_lg - m);
    den = sp;
    for (int base = k0; base < k1; base += 64) {
      int k = base + lane;
      bool act = (k < k1);
      int c = act ? (int)col[k] : 0;
      float p = act ? __expf(lrelu(es[c] + edd) - m) : 0.f;
      den += wave_sum(p);
      int len = min(64, k1 - base);
      for (int j = 0; j < len; j += 8) {
        int i0 = min(j + g8, 63);
        int c0 = __shfl(c, i0);
        float p0 = __shfl(p, i0);
        uint4 v0 = *(const uint4*)(Hb + (((size_t)c0 << 7) + l8 * 16));
        acc[0] += p0 * bf_lo(v0.x); acc[1] += p0 * bf_hi(v0.x);
        acc[2] += p0 * bf_lo(v0.y); acc[3] += p0 * bf_hi(v0.y);
        acc[4] += p0 * bf_lo(v0.z); acc[5] += p0 * bf_hi(v0.z);
        acc[6] += p0 * bf_lo(v0.w); acc[7] += p0 * bf_hi(v0.w);
      }
    }
  }

  // reduce across the 8 groups
#pragma unroll
  for (int i = 0; i < 8; ++i) {
    acc[i] += __shfl_xor(acc[i], 8, 64);
    acc[i] += __shfl_xor(acc[i], 16, 64);
    acc[i] += __shfl_xor(acc[i], 32, 64);
  }

  uint4 hv = *(const uint4*)(Hb + (((size_t)n << 7) + l8 * 16));
  acc[0] += sp * bf_lo(hv.x); acc[1] += sp * bf_hi(hv.x);
  acc[2] += sp * bf_lo(hv.y); acc[3] += sp * bf_hi(hv.y);
  acc[4] += sp * bf_lo(hv.z); acc[5] += sp * bf_hi(hv.z);
  acc[6] += sp * bf_lo(hv.w); acc[7] += sp * bf_hi(hv.w);

  float inv = 1.f / den;
  float4 bv0 = *(const float4*)(bias + l8 * 8);
  float4 bv1 = *(const float4*)(bias + l8 * 8 + 4);
  float4 w0, w1;
  w0.x = acc[0] * inv + bv0.x; w0.y = acc[1] * inv + bv0.y;
  w0.z = acc[2] * inv + bv0.z; w0.w = acc[3] * inv + bv0.w;
  w1.x = acc[4] * inv + bv1.x; w1.y = acc[5] * inv + bv1.y;
  w1.z = acc[6] * inv + bv1.z; w1.w = acc[7] * inv + bv1.w;
  if (RELU) {
    w0.x = fmaxf(w0.x, 0.f); w0.y = fmaxf(w0.y, 0.f);
    w0.z = fmaxf(w0.z, 0.f); w0.w = fmaxf(w0.w, 0.f);
    w1.x = fmaxf(w1.x, 0.f); w1.y = fmaxf(w1.y, 0.f);
    w1.z = fmaxf(w1.z, 0.f); w1.w = fmaxf(w1.w, 0.f);
  }
  if (g8 == 0) {
    char* op = (char*)outX + (((size_t)n << 8) + l8 * 32);
    *(float4*)op = w0;
    *(float4*)(op + 16) = w1;
  }
}

// ---------------------------------------------------------------------------

extern "C" void kernel_launch(void* const* d_in, const int* in_sizes, int n_in,
                              void* d_out, int out_size, void* d_ws, size_t ws_size,
                              hipStream_t stream) {
  const int C_HID = in_sizes[3];            // 128
  const int C_FIN = in_sizes[11];           // 64
  const int C_IN  = in_sizes[2] / C_HID;    // 128
  const int N     = in_sizes[0] / C_IN;     // 50000
  const int E     = in_sizes[1] / 2;        // 1.6M
  const int NPAD  = ((N + 63) / 64) * 64;

  const float* x = (const float*)d_in[0];
  const int* ei  = (const int*)d_in[1];
  const int* src = ei;
  const int* dst = ei + E;

  const float* W0  = (const float*)d_in[2];
  const float* as0 = (const float*)d_in[3];
  const float* ad0 = (const float*)d_in[4];
  const float* b0  = (const float*)d_in[5];
  const float* W1  = (const float*)d_in[6];
  const float* as1 = (const float*)d_in[7];
  const float* ad1 = (const float*)d_in[8];
  const float* b1  = (const float*)d_in[9];
  const float* W2  = (const float*)d_in[10];
  const float* as2 = (const float*)d_in[11];
  const float* ad2 = (const float*)d_in[12];
  const float* b2  = (const float*)d_in[13];

  // Workspace layout (256B aligned)
  char* base = (char*)d_ws;
  size_t off = 0;
  auto alloc = [&](size_t bytes) -> char* {
    char* p = base + off;
    off = (off + bytes + 255) & ~((size_t)255);
    return p;
  };
  const int PBLK = 512;                     // partition blocks
  const int NBK  = (N + 511) >> 9;          // buckets of 512 dst nodes (<=128)
  const int M    = NBK * PBLK;              // offset-matrix size
  const int NCH  = (N + 255) / 256;
  const int MCH  = (M + 255) / 256;
  const int SCH  = (NCH > MCH ? NCH : MCH);

  unsigned short* XB  = (unsigned short*)alloc((size_t)NPAD * C_HID * 2);
  unsigned short* H   = (unsigned short*)alloc((size_t)N * C_HID * 2);
  float* ES    = (float*)alloc((size_t)N * sizeof(float));
  float* ED    = (float*)alloc((size_t)N * sizeof(float));
  int*   RP    = (int*)alloc((size_t)(N + 1) * sizeof(int));
  int*   WP    = (int*)alloc((size_t)N * sizeof(int));
  void*  COL   = (void*)alloc((size_t)E * sizeof(int));   // u16 uses half
  int*   DEG   = (int*)alloc((size_t)N * sizeof(int));
  int*   CSUM  = (int*)alloc((size_t)SCH * sizeof(int));
  int*   HMAT  = (int*)alloc((size_t)M * sizeof(int));
  int*   OFF   = (int*)alloc((size_t)M * sizeof(int));
  unsigned* BE = (unsigned*)alloc((size_t)E * sizeof(unsigned));
  (void)ws_size;

  const int wgrid = (N + 3) / 4;
  const int mgrid = NPAD / 64;
  const bool u16 = (N <= 65535);

  // ---- CSR build ----
  if (u16) {
    const int CHUNK = (E + PBLK - 1) / PBLK;
    hist_only<<<PBLK, 256, 0, stream>>>(dst, HMAT, E, NBK, CHUNK);
    scan_partial<<<MCH, 256, 0, stream>>>(HMAT, CSUM, M);
    scan_chunks<<<1, 256, 0, stream>>>(CSUM, MCH);
    scan_final_excl<<<MCH, 256, 0, stream>>>(HMAT, CSUM, OFF, M);
    place_pass<<<PBLK, 256, 0, stream>>>(src, dst, OFF, BE, E, NBK, CHUNK);
    bucket_final<<<NBK, 256, 0, stream>>>(BE, OFF, RP, (unsigned short*)COL,
                                          E, N, NBK, PBLK);
  } else {
    hipMemsetAsync(DEG, 0, (size_t)N * sizeof(int), stream);
    const int ET256 = (E + 255) / 256;
    csr_count<<<ET256, 256, 0, stream>>>(dst, DEG, E);
    scan_partial<<<NCH, 256, 0, stream>>>(DEG, CSUM, N);
    scan_chunks<<<1, 256, 0, stream>>>(CSUM, NCH);
    scan_final<<<NCH, 256, 0, stream>>>(DEG, CSUM, RP, WP, N, E);
    const int NPASS = 8;
    const int range = (N + NPASS - 1) / NPASS;
    csr_scatter_ranged<<<2048, 256, 0, stream>>>(src, dst, WP, (int*)COL, E,
                                                 range, NPASS);
  }

  auto run_layers = [&](auto* col) {
    using IT = typename std::remove_pointer<decltype(col)>::type;
    // ---- Layer 0: x(fp32) -> H(+es/ed) -> XB (relu, bf16) ----
    gemm_mfma<128, true><<<mgrid, 256, 0, stream>>>(x, W0, as0, ad0, H, ES, ED, N);
    gat_fused128<true, IT><<<wgrid, 256, 0, stream>>>(RP, col, ES, ED, H, b0, XB, N);
    // ---- Layer 1: XB -> H(+es/ed) -> XB (relu, bf16) ----
    gemm_mfma<128, false><<<mgrid, 256, 0, stream>>>(XB, W1, as1, ad1, H, ES, ED, N);
    gat_fused128<true, IT><<<wgrid, 256, 0, stream>>>(RP, col, ES, ED, H, b1, XB, N);
    // ---- Layer 2: XB -> H(+es/ed) -> d_out (no relu, fp32) ----
    gemm_mfma<64, false><<<mgrid, 256, 0, stream>>>(XB, W2, as2, ad2, H, ES, ED, N);
    gat_fused64<false, IT><<<wgrid, 256, 0, stream>>>(RP, col, ES, ED, H, b2,
                                                      (float*)d_out, N);
  };

  if (u16) run_layers((unsigned short*)COL);
  else     run_layers((int*)COL);
  (void)out_size; (void)n_in;
}